// Round 3
// baseline (2919.270 us; speedup 1.0000x reference)
//
#include <hip/hip_runtime.h>

// LSTM S=512 B=64 I=256 H=512, gates f,i,o,g (4H=2048).
// Persistent-register weights; fused [x_t|h] @ W recurrent GEMM.
// R3: self-validating tagged h words (bf16<<16 | step_tag) exchanged via
// relaxed agent-scope (IF-coherent) loads/stores. No flags, no counters,
// no producer drain: one IF round trip per step on the consumer side.

#define S_LEN 512
#define NBLK  128

typedef __attribute__((ext_vector_type(8))) __bf16 bf16x8;
typedef __attribute__((ext_vector_type(4))) float  f32x4;

// workspace layout (bytes)
#define OFF_W    ((size_t)0)          // swizzled W: 3,145,728
#define OFF_BIAS ((size_t)3145728)    // 2048 f32
#define OFF_H    ((size_t)3162112)    // tagged h double buffer: 2*64*512*4 = 262,144
#define OFF_X    ((size_t)4194304)    // x bf16: 16,777,216

// ---- prelude: x fp32 -> bf16 ----
__global__ void k_conv_x(const float* __restrict__ x, __bf16* __restrict__ xb) {
  int i = blockIdx.x * 256 + threadIdx.x;      // 2,097,152 threads exactly
  float4 v = ((const float4*)x)[i];
  union { __bf16 b[4]; uint2 u; } p;
  p.b[0] = (__bf16)v.x; p.b[1] = (__bf16)v.y;
  p.b[2] = (__bf16)v.z; p.b[3] = (__bf16)v.w;
  ((uint2*)xb)[i] = p.u;
}

// ---- prelude: W -> bf16, MFMA-B-fragment-swizzled ----
// frag tid = ((hs*4+g)*24 + kk)*64 + L ; lane L holds 8 bf16:
// W[k = kk*32 + (L>>4)*8 + j][col = hs*16 + (L&15)] ; k<256 -> Wx else Wh.
__global__ void k_conv_w(const float* __restrict__ wxf, const float* __restrict__ whf,
                         const float* __restrict__ wxi, const float* __restrict__ whi,
                         const float* __restrict__ wxo, const float* __restrict__ who,
                         const float* __restrict__ wxg, const float* __restrict__ whg,
                         __bf16* __restrict__ Wswz) {
  int tid = blockIdx.x * 256 + threadIdx.x;    // 196,608 threads exactly
  int L = tid & 63;
  int q = tid >> 6;
  int kk = q % 24;
  int q2 = q / 24;
  int g  = q2 & 3;
  int hs = q2 >> 2;
  const float* Wx = (g == 0) ? wxf : (g == 1) ? wxi : (g == 2) ? wxo : wxg;
  const float* Wh = (g == 0) ? whf : (g == 1) ? whi : (g == 2) ? who : whg;
  int col = hs * 16 + (L & 15);
  int k0  = kk * 32 + (L >> 4) * 8;
  union { __bf16 b[8]; uint4 u; } p;
#pragma unroll
  for (int j = 0; j < 8; ++j) {
    int k = k0 + j;
    float v = (k < 256) ? Wx[k * 512 + col] : Wh[(k - 256) * 512 + col];
    p.b[j] = (__bf16)v;
  }
  ((uint4*)Wswz)[tid] = p.u;
}

// ---- prelude: combined bias b = bx + bh, layout [gate][512] ----
__global__ void k_conv_bias(const float* __restrict__ bxf, const float* __restrict__ bhf,
                            const float* __restrict__ bxi, const float* __restrict__ bhi,
                            const float* __restrict__ bxo, const float* __restrict__ bho,
                            const float* __restrict__ bxg, const float* __restrict__ bhg,
                            float* __restrict__ bc) {
  int n = blockIdx.x * 256 + threadIdx.x;      // 2048 exactly
  int g = n >> 9, h = n & 511;
  const float* bx = (g == 0) ? bxf : (g == 1) ? bxi : (g == 2) ? bxo : bxg;
  const float* bh = (g == 0) ? bhf : (g == 1) ? bhi : (g == 2) ? bho : bhg;
  bc[n] = bx[h] + bh[h];
}

__device__ __forceinline__ float sigm(float x) { return 1.f / (1.f + __expf(-x)); }
__device__ __forceinline__ float tanh_f(float x) { return 1.f - 2.f / (1.f + __expf(2.f * x)); }

// ---- main recurrent kernel ----
// block (mt, hs): mt = batch tile (16 rows), hs = hidden slice (16 units).
// Wave w owns W kk-set: w0 {0..3 (x), 8..15 (h[0,256))}, w1 {4..7 (x), 16..23 (h[256,512))}.
// Tagged-h protocol: word = bf16(h)<<16 | tag; input of step t carries tag t.
__global__ __launch_bounds__(128, 1) void lstm_seq(
    const __bf16* __restrict__ Wswz, const float* __restrict__ bias,
    const __bf16* __restrict__ xb, unsigned int* __restrict__ hb,
    float* __restrict__ out) {
  const int tid  = threadIdx.x;
  const int w    = tid >> 6;
  const int L    = tid & 63;
  const int quad = L >> 4;
  const int lc   = L & 15;
  const int mt   = blockIdx.x & 3;
  const int hs   = blockIdx.x >> 2;

  __shared__ f32x4 red[4][64];

  // persistent weight fragments: 12 kk-frags x 4 gates
  bf16x8 Wf[12][4];
  {
    const uint4* wp = (const uint4*)Wswz;
#pragma unroll
    for (int j = 0; j < 12; ++j) {
      int kk = (w == 0) ? ((j < 4) ? j : j + 4) : ((j < 4) ? j + 4 : j + 12);
#pragma unroll
      for (int g = 0; g < 4; ++g) {
        uint4 u = wp[(((size_t)(hs * 4 + g) * 24 + kk) << 6) + L];
        Wf[j][g] = __builtin_bit_cast(bf16x8, u);
      }
    }
  }
  float bsv[4];
#pragma unroll
  for (int g = 0; g < 4; ++g) bsv[g] = bias[g * 512 + hs * 16 + lc];

  const int row = mt * 16 + lc;              // A-row this lane loads
  const __bf16* px = xb + (size_t)row * 256 + w * 128 + quad * 8;
  unsigned int* hbase = hb + (size_t)row * 512 + w * 256 + quad * 8;

  f32x4 cst = {0.f, 0.f, 0.f, 0.f};          // cell state (wave1 only)

  for (int t = 0; t < S_LEN; ++t) {
    const unsigned int* hrw = hbase + (size_t)(t & 1) * 32768;

    // issue tagged-h loads for all 8 frags (relaxed agent scope -> IF)
    unsigned long long hq[8][4];
#pragma unroll
    for (int f = 0; f < 8; ++f)
#pragma unroll
      for (int p = 0; p < 4; ++p)
        hq[f][p] = __hip_atomic_load(
            (const unsigned long long*)(hrw + f * 32) + p,
            __ATOMIC_RELAXED, __HIP_MEMORY_SCOPE_AGENT);

    // x contribution in the shadow of the h loads
    f32x4 acc[4] = {{0,0,0,0},{0,0,0,0},{0,0,0,0},{0,0,0,0}};
#pragma unroll
    for (int f = 0; f < 4; ++f) {
      bf16x8 a = __builtin_bit_cast(bf16x8, *(const uint4*)(px + f * 32));
#pragma unroll
      for (int g = 0; g < 4; ++g)
        acc[g] = __builtin_amdgcn_mfma_f32_16x16x32_bf16(a, Wf[f][g], acc[g], 0, 0, 0);
    }

    // validate tags; retry = reload (one IF round trip per iteration)
    const unsigned long long tag2 =
        (unsigned long long)(unsigned)t | ((unsigned long long)(unsigned)t << 32);
    for (;;) {
      unsigned long long m = 0;
#pragma unroll
      for (int f = 0; f < 8; ++f)
#pragma unroll
        for (int p = 0; p < 4; ++p)
          m |= (hq[f][p] ^ tag2) & 0x0000FFFF0000FFFFULL;
      if (__all(m == 0)) break;
#pragma unroll
      for (int f = 0; f < 8; ++f)
#pragma unroll
        for (int p = 0; p < 4; ++p)
          hq[f][p] = __hip_atomic_load(
              (const unsigned long long*)(hrw + f * 32) + p,
              __ATOMIC_RELAXED, __HIP_MEMORY_SCOPE_AGENT);
    }

    // unpack (v_perm: take high16 of each tagged word) + h MFMAs
#pragma unroll
    for (int f = 0; f < 8; ++f) {
      uint4 pk;
      pk.x = __builtin_amdgcn_perm((unsigned)(hq[f][0] >> 32), (unsigned)hq[f][0], 0x07060302u);
      pk.y = __builtin_amdgcn_perm((unsigned)(hq[f][1] >> 32), (unsigned)hq[f][1], 0x07060302u);
      pk.z = __builtin_amdgcn_perm((unsigned)(hq[f][2] >> 32), (unsigned)hq[f][2], 0x07060302u);
      pk.w = __builtin_amdgcn_perm((unsigned)(hq[f][3] >> 32), (unsigned)hq[f][3], 0x07060302u);
      bf16x8 a = __builtin_bit_cast(bf16x8, pk);
#pragma unroll
      for (int g = 0; g < 4; ++g)
        acc[g] = __builtin_amdgcn_mfma_f32_16x16x32_bf16(a, Wf[4 + f][g], acc[g], 0, 0, 0);
    }

    if (w == 0) {
#pragma unroll
      for (int g = 0; g < 4; ++g) red[g][L] = acc[g];
    }
    __syncthreads();

    if (w == 1) {
      unsigned int* hw = hb + (size_t)((t + 1) & 1) * 32768;
#pragma unroll
      for (int g = 0; g < 4; ++g) acc[g] += red[g][L];
      float* oseq = out + (size_t)t * 32768;
      const int col = hs * 16 + lc;
      const unsigned int otag = (unsigned)(t + 1) & 0xffffu;
#pragma unroll
      for (int r = 0; r < 4; ++r) {
        float fg = sigm(acc[0][r] + bsv[0]);
        float ig = sigm(acc[1][r] + bsv[1]);
        float og = sigm(acc[2][r] + bsv[2]);
        float gg = tanh_f(acc[3][r] + bsv[3]);
        float cn = fg * cst[r] + ig * gg;
        cst[r] = cn;
        float hv = og * tanh_f(cn);
        int orow = mt * 16 + quad * 4 + r;
        oseq[orow * 512 + col] = hv;
        unsigned short hbits = __builtin_bit_cast(unsigned short, (__bf16)hv);
        // fire-and-forget tagged store; no drain, no flag
        __hip_atomic_store(&hw[orow * 512 + col],
                           ((unsigned)hbits << 16) | otag,
                           __ATOMIC_RELAXED, __HIP_MEMORY_SCOPE_AGENT);
        if (t == S_LEN - 1) {
          out[16777216 + orow * 512 + col] = hv;               // final h
          out[16777216 + 32768 + orow * 512 + col] = cn;       // final c
        }
      }
    }
    px += 16384;
  }
}

extern "C" void kernel_launch(void* const* d_in, const int* in_sizes, int n_in,
                              void* d_out, int out_size, void* d_ws, size_t ws_size,
                              hipStream_t stream) {
  char* ws = (char*)d_ws;
  __bf16*       Wswz = (__bf16*)(ws + OFF_W);
  float*        bias = (float*)(ws + OFF_BIAS);
  unsigned int* hb   = (unsigned int*)(ws + OFF_H);
  __bf16*       xb   = (__bf16*)(ws + OFF_X);

  // zero tagged-h buffer 0: value 0 with tag 0 == valid step-0 input.
  // buffer 1 keeps 0xAA poison; tag 0xAAAA never matches a real step tag.
  hipMemsetAsync(ws + OFF_H, 0, 131072, stream);

  k_conv_x<<<8192, 256, 0, stream>>>((const float*)d_in[0], xb);
  k_conv_w<<<768, 256, 0, stream>>>(
      (const float*)d_in[1],  (const float*)d_in[3],    // f: Wx, Wh
      (const float*)d_in[5],  (const float*)d_in[7],    // i
      (const float*)d_in[9],  (const float*)d_in[11],   // o
      (const float*)d_in[13], (const float*)d_in[15],   // g
      Wswz);
  k_conv_bias<<<8, 256, 0, stream>>>(
      (const float*)d_in[2],  (const float*)d_in[4],
      (const float*)d_in[6],  (const float*)d_in[8],
      (const float*)d_in[10], (const float*)d_in[12],
      (const float*)d_in[14], (const float*)d_in[16],
      bias);
  lstm_seq<<<NBLK, 128, 0, stream>>>(Wswz, bias, xb, hb, (float*)d_out);
}

// Round 4
// 2782.814 us; speedup vs baseline: 1.0490x; 1.0490x over previous
//
#include <hip/hip_runtime.h>

// LSTM S=512 B=64 I=256 H=512, gates f,i,o,g (4H=2048).
// Persistent-register weights; fused [x_t|h] @ W recurrent GEMM.
// R4: tagged-h protocol (bf16<<16 | step_tag, relaxed agent-scope) kept from
// R3, but producer issues the 4 tagged-h stores FIRST and defers all fp32
// output stores until after them (VMEM issues in order per wave — R3 had h
// queued behind HBM stores). Final h/c hoisted out of the loop; LDS reduce
// parity-double-buffered.

#define S_LEN 512
#define NBLK  128

typedef __attribute__((ext_vector_type(8))) __bf16 bf16x8;
typedef __attribute__((ext_vector_type(4))) float  f32x4;

// workspace layout (bytes)
#define OFF_W    ((size_t)0)          // swizzled W: 3,145,728
#define OFF_BIAS ((size_t)3145728)    // 2048 f32
#define OFF_H    ((size_t)3162112)    // tagged h double buffer: 2*64*512*4 = 262,144
#define OFF_X    ((size_t)4194304)    // x bf16: 16,777,216

// ---- prelude: x fp32 -> bf16 ----
__global__ void k_conv_x(const float* __restrict__ x, __bf16* __restrict__ xb) {
  int i = blockIdx.x * 256 + threadIdx.x;      // 2,097,152 threads exactly
  float4 v = ((const float4*)x)[i];
  union { __bf16 b[4]; uint2 u; } p;
  p.b[0] = (__bf16)v.x; p.b[1] = (__bf16)v.y;
  p.b[2] = (__bf16)v.z; p.b[3] = (__bf16)v.w;
  ((uint2*)xb)[i] = p.u;
}

// ---- prelude: W -> bf16, MFMA-B-fragment-swizzled ----
// frag tid = ((hs*4+g)*24 + kk)*64 + L ; lane L holds 8 bf16:
// W[k = kk*32 + (L>>4)*8 + j][col = hs*16 + (L&15)] ; k<256 -> Wx else Wh.
__global__ void k_conv_w(const float* __restrict__ wxf, const float* __restrict__ whf,
                         const float* __restrict__ wxi, const float* __restrict__ whi,
                         const float* __restrict__ wxo, const float* __restrict__ who,
                         const float* __restrict__ wxg, const float* __restrict__ whg,
                         __bf16* __restrict__ Wswz) {
  int tid = blockIdx.x * 256 + threadIdx.x;    // 196,608 threads exactly
  int L = tid & 63;
  int q = tid >> 6;
  int kk = q % 24;
  int q2 = q / 24;
  int g  = q2 & 3;
  int hs = q2 >> 2;
  const float* Wx = (g == 0) ? wxf : (g == 1) ? wxi : (g == 2) ? wxo : wxg;
  const float* Wh = (g == 0) ? whf : (g == 1) ? whi : (g == 2) ? who : whg;
  int col = hs * 16 + (L & 15);
  int k0  = kk * 32 + (L >> 4) * 8;
  union { __bf16 b[8]; uint4 u; } p;
#pragma unroll
  for (int j = 0; j < 8; ++j) {
    int k = k0 + j;
    float v = (k < 256) ? Wx[k * 512 + col] : Wh[(k - 256) * 512 + col];
    p.b[j] = (__bf16)v;
  }
  ((uint4*)Wswz)[tid] = p.u;
}

// ---- prelude: combined bias b = bx + bh, layout [gate][512] ----
__global__ void k_conv_bias(const float* __restrict__ bxf, const float* __restrict__ bhf,
                            const float* __restrict__ bxi, const float* __restrict__ bhi,
                            const float* __restrict__ bxo, const float* __restrict__ bho,
                            const float* __restrict__ bxg, const float* __restrict__ bhg,
                            float* __restrict__ bc) {
  int n = blockIdx.x * 256 + threadIdx.x;      // 2048 exactly
  int g = n >> 9, h = n & 511;
  const float* bx = (g == 0) ? bxf : (g == 1) ? bxi : (g == 2) ? bxo : bxg;
  const float* bh = (g == 0) ? bhf : (g == 1) ? bhi : (g == 2) ? bho : bhg;
  bc[n] = bx[h] + bh[h];
}

__device__ __forceinline__ float sigm(float x) { return 1.f / (1.f + __expf(-x)); }
__device__ __forceinline__ float tanh_f(float x) { return 1.f - 2.f / (1.f + __expf(2.f * x)); }

// ---- main recurrent kernel ----
// block (mt, hs): mt = batch tile (16 rows), hs = hidden slice (16 units).
// Wave w owns W kk-set: w0 {0..3 (x), 8..15 (h[0,256))}, w1 {4..7 (x), 16..23 (h[256,512))}.
// Tagged-h protocol: word = bf16(h)<<16 | tag; input of step t carries tag t.
__global__ __launch_bounds__(128, 1) void lstm_seq(
    const __bf16* __restrict__ Wswz, const float* __restrict__ bias,
    const __bf16* __restrict__ xb, unsigned int* __restrict__ hb,
    float* __restrict__ out) {
  const int tid  = threadIdx.x;
  const int w    = tid >> 6;
  const int L    = tid & 63;
  const int quad = L >> 4;
  const int lc   = L & 15;
  const int mt   = blockIdx.x & 3;
  const int hs   = blockIdx.x >> 2;

  __shared__ f32x4 red[2][4][64];   // parity double-buffered partial sums

  // persistent weight fragments: 12 kk-frags x 4 gates
  bf16x8 Wf[12][4];
  {
    const uint4* wp = (const uint4*)Wswz;
#pragma unroll
    for (int j = 0; j < 12; ++j) {
      int kk = (w == 0) ? ((j < 4) ? j : j + 4) : ((j < 4) ? j + 4 : j + 12);
#pragma unroll
      for (int g = 0; g < 4; ++g) {
        uint4 u = wp[(((size_t)(hs * 4 + g) * 24 + kk) << 6) + L];
        Wf[j][g] = __builtin_bit_cast(bf16x8, u);
      }
    }
  }
  float bsv[4];
#pragma unroll
  for (int g = 0; g < 4; ++g) bsv[g] = bias[g * 512 + hs * 16 + lc];

  const int row = mt * 16 + lc;              // A-row this lane loads
  const __bf16* px = xb + (size_t)row * 256 + w * 128 + quad * 8;
  unsigned int* hbase = hb + (size_t)row * 512 + w * 256 + quad * 8;

  f32x4 cst = {0.f, 0.f, 0.f, 0.f};          // cell state (wave1 only)
  float hv[4] = {0.f, 0.f, 0.f, 0.f};        // last-step h (wave1 only)
  const int col = hs * 16 + lc;

  for (int t = 0; t < S_LEN; ++t) {
    const int par = t & 1;
    const unsigned int* hrw = hbase + (size_t)par * 32768;

    // issue tagged-h loads for all 8 frags (relaxed agent scope -> IF)
    unsigned long long hq[8][4];
#pragma unroll
    for (int f = 0; f < 8; ++f)
#pragma unroll
      for (int p = 0; p < 4; ++p)
        hq[f][p] = __hip_atomic_load(
            (const unsigned long long*)(hrw + f * 32) + p,
            __ATOMIC_RELAXED, __HIP_MEMORY_SCOPE_AGENT);

    // x contribution in the shadow of the h loads
    f32x4 acc[4] = {{0,0,0,0},{0,0,0,0},{0,0,0,0},{0,0,0,0}};
#pragma unroll
    for (int f = 0; f < 4; ++f) {
      bf16x8 a = __builtin_bit_cast(bf16x8, *(const uint4*)(px + f * 32));
#pragma unroll
      for (int g = 0; g < 4; ++g)
        acc[g] = __builtin_amdgcn_mfma_f32_16x16x32_bf16(a, Wf[f][g], acc[g], 0, 0, 0);
    }

    // validate tags; retry = reload (tags are sticky-valid once written)
    const unsigned long long tag2 =
        (unsigned long long)(unsigned)t | ((unsigned long long)(unsigned)t << 32);
    for (;;) {
      unsigned long long m = 0;
#pragma unroll
      for (int f = 0; f < 8; ++f)
#pragma unroll
        for (int p = 0; p < 4; ++p)
          m |= (hq[f][p] ^ tag2) & 0x0000FFFF0000FFFFULL;
      if (__all(m == 0)) break;
#pragma unroll
      for (int f = 0; f < 8; ++f)
#pragma unroll
        for (int p = 0; p < 4; ++p)
          hq[f][p] = __hip_atomic_load(
              (const unsigned long long*)(hrw + f * 32) + p,
              __ATOMIC_RELAXED, __HIP_MEMORY_SCOPE_AGENT);
    }

    // unpack (v_perm: take high16 of each tagged word) + h MFMAs
#pragma unroll
    for (int f = 0; f < 8; ++f) {
      uint4 pk;
      pk.x = __builtin_amdgcn_perm((unsigned)(hq[f][0] >> 32), (unsigned)hq[f][0], 0x07060302u);
      pk.y = __builtin_amdgcn_perm((unsigned)(hq[f][1] >> 32), (unsigned)hq[f][1], 0x07060302u);
      pk.z = __builtin_amdgcn_perm((unsigned)(hq[f][2] >> 32), (unsigned)hq[f][2], 0x07060302u);
      pk.w = __builtin_amdgcn_perm((unsigned)(hq[f][3] >> 32), (unsigned)hq[f][3], 0x07060302u);
      bf16x8 a = __builtin_bit_cast(bf16x8, pk);
#pragma unroll
      for (int g = 0; g < 4; ++g)
        acc[g] = __builtin_amdgcn_mfma_f32_16x16x32_bf16(a, Wf[4 + f][g], acc[g], 0, 0, 0);
    }

    if (w == 0) {
#pragma unroll
      for (int g = 0; g < 4; ++g) red[par][g][L] = acc[g];
    }
    __syncthreads();

    if (w == 1) {
      unsigned int* hw = hb + (size_t)(1 - par) * 32768;
#pragma unroll
      for (int g = 0; g < 4; ++g) acc[g] += red[par][g][L];
      const unsigned int otag = (unsigned)(t + 1) & 0xffffu;
      // pass 1: gates + tagged-h stores ONLY (these are what 32 blocks wait on)
#pragma unroll
      for (int r = 0; r < 4; ++r) {
        float fg = sigm(acc[0][r] + bsv[0]);
        float ig = sigm(acc[1][r] + bsv[1]);
        float og = sigm(acc[2][r] + bsv[2]);
        float gg = tanh_f(acc[3][r] + bsv[3]);
        float cn = fg * cst[r] + ig * gg;
        cst[r] = cn;
        float h = og * tanh_f(cn);
        hv[r] = h;
        unsigned short hbits = __builtin_bit_cast(unsigned short, (__bf16)h);
        __hip_atomic_store(&hw[(mt * 16 + quad * 4 + r) * 512 + col],
                           ((unsigned)hbits << 16) | otag,
                           __ATOMIC_RELAXED, __HIP_MEMORY_SCOPE_AGENT);
      }
      // pass 2: fp32 sequence-output stores (HBM, nobody waits on these)
      float* oseq = out + (size_t)t * 32768;
#pragma unroll
      for (int r = 0; r < 4; ++r)
        oseq[(mt * 16 + quad * 4 + r) * 512 + col] = hv[r];
    }
    px += 16384;
  }

  // final h / final c (from last iteration's registers)
  if (w == 1) {
#pragma unroll
    for (int r = 0; r < 4; ++r) {
      int orow = mt * 16 + quad * 4 + r;
      out[16777216 + orow * 512 + col] = hv[r];
      out[16777216 + 32768 + orow * 512 + col] = cst[r];
    }
  }
}

extern "C" void kernel_launch(void* const* d_in, const int* in_sizes, int n_in,
                              void* d_out, int out_size, void* d_ws, size_t ws_size,
                              hipStream_t stream) {
  char* ws = (char*)d_ws;
  __bf16*       Wswz = (__bf16*)(ws + OFF_W);
  float*        bias = (float*)(ws + OFF_BIAS);
  unsigned int* hb   = (unsigned int*)(ws + OFF_H);
  __bf16*       xb   = (__bf16*)(ws + OFF_X);

  // zero tagged-h buffer 0: value 0 with tag 0 == valid step-0 input.
  // buffer 1 keeps 0xAA poison; tag 0xAAAA never matches a real step tag.
  hipMemsetAsync(ws + OFF_H, 0, 131072, stream);

  k_conv_x<<<8192, 256, 0, stream>>>((const float*)d_in[0], xb);
  k_conv_w<<<768, 256, 0, stream>>>(
      (const float*)d_in[1],  (const float*)d_in[3],    // f: Wx, Wh
      (const float*)d_in[5],  (const float*)d_in[7],    // i
      (const float*)d_in[9],  (const float*)d_in[11],   // o
      (const float*)d_in[13], (const float*)d_in[15],   // g
      Wswz);
  k_conv_bias<<<8, 256, 0, stream>>>(
      (const float*)d_in[2],  (const float*)d_in[4],
      (const float*)d_in[6],  (const float*)d_in[8],
      (const float*)d_in[10], (const float*)d_in[12],
      (const float*)d_in[14], (const float*)d_in[16],
      bias);
  lstm_seq<<<NBLK, 128, 0, stream>>>(Wswz, bias, xb, hb, (float*)d_out);
}